// Round 2
// baseline (2507.936 us; speedup 1.0000x reference)
//
#include <hip/hip_runtime.h>

#define SS 128
#define BB 32
#define HH 512
#define VV 8000
#define VPAD 8064

typedef __bf16 bf16_t;
typedef __bf16 bf16x8 __attribute__((ext_vector_type(8)));
typedef float  floatx4 __attribute__((ext_vector_type(4)));
typedef unsigned int u32x4 __attribute__((ext_vector_type(4)));

__device__ __forceinline__ float sigmoidf_(float x) { return 1.0f / (1.0f + expf(-x)); }
__device__ __forceinline__ bf16x8 as_bf16x8(u32x4 v) { return __builtin_bit_cast(bf16x8, v); }

// ---------------- workspace layout (bytes) ----------------
#define WS_FLG   0                       // flags[4][64] int = 1024 B (per-WG "steps done")
#define WS_HHI   1024                    // h ring hi [2d][2l][4 slot][32][512] bf16 = 524288
#define WS_HLO   (WS_HHI + 524288)       // h ring lo = 524288
#define WS_XHI   (WS_HLO + 524288)       // x hi [128][32][512] bf16 = 4194304
#define WS_XLO   (WS_XHI + 4194304)      // x lo = 4194304
#define WS_HOUT  (WS_XLO + 4194304)      // top-layer h [2][128][32][512] bf16 = 8388608
#define WS_WP    (WS_HOUT + 8388608)     // proj weights [2][8064][512] bf16 = 16515072
#define MEMSET_BYTES WS_XHI              // zero flags + h ring

// LDS: weights 131072 + pbuf 4*32*36*4 = 18432 + bsum 128 -> 149632 (< 160 KiB)
#define SMEM_BYTES 149632

// ---------------- prep kernels ----------------

__global__ __launch_bounds__(256)
void prep_x(const float* __restrict__ x, bf16_t* __restrict__ xh, bf16_t* __restrict__ xl) {
    int i = blockIdx.x * 256 + threadIdx.x;   // 128*32*512 = 2097152 exact
    float v = x[i];
    bf16_t h = (bf16_t)v;
    xh[i] = h;
    xl[i] = (bf16_t)(v - (float)h);
}

__global__ __launch_bounds__(256)
void prep_wp(const float* __restrict__ Wf, const float* __restrict__ Wb, bf16_t* __restrict__ Wp) {
    int i = blockIdx.x * 256 + threadIdx.x;   // 2*8064*512 = 8257536 exact
    int k   = i & 511;
    int rd  = i >> 9;
    int row = rd % 8064;
    int d   = rd / 8064;
    const float* W = d ? Wb : Wf;
    Wp[i] = (row < VV) ? (bf16_t)W[(size_t)row * 512 + k] : (bf16_t)0.0f;
}

// ---------------- persistent LSTM ----------------
// 256 WGs x 512 thr, 1 WG/CU. WG = (d, l, s): 8 h-cols x 4 gates of one (dir,layer).
// Weights (split hi/lo) in LDS, pre-swizzled MFMA fragment order.
// Wave kq (0..7): half = kq>>2 (0: input A, 1: recurrent A), kb = kq&3 (128-k block).
//
// Sync design (this round):
//  - POLLER IS WAVE 7 (recurrent half): no x prefetch ahead of it (vmcnt issue-order
//    coupling would make the poll eat the x HBM-miss latency), and it is not an
//    epilogue wave (poll overlaps previous-step epilogue).
//  - 3 barriers/step (was 4): pbuf accumulation is ds_add_f32 (atomicAdd) from all
//    8 waves onto a zeroed buffer; epilogue zeroes cells after reading them.
//  - sc1 h loads issued j-major; vmcnt(8) covers j0/j1, register-tied vmcnt(0)
//    covers j2/j3 (MFMA overlaps half the MALL latency).
//  - h ring: sc1 stores (write-through to MALL) / sc1 loads. No fences anywhere.

__global__ __launch_bounds__(512, 2)
void lstm_persist(const float* __restrict__ Wf_ih, const float* __restrict__ Wf_hh,
                  const float* __restrict__ Wb_ih, const float* __restrict__ Wb_hh,
                  const float* __restrict__ bf_ih, const float* __restrict__ bf_hh,
                  const float* __restrict__ bb_ih, const float* __restrict__ bb_hh,
                  const bf16_t* __restrict__ x_hi, const bf16_t* __restrict__ x_lo,
                  bf16_t* __restrict__ h_hi, bf16_t* __restrict__ h_lo,
                  bf16_t* __restrict__ hout, int* __restrict__ flg)
{
    extern __shared__ char smem[];
    bf16_t* wlds = (bf16_t*)smem;                     // 128 KB weight fragments
    float*  pbuf = (float*)(smem + 131072);           // [4 kb][32 row][36] k-partials
    float*  bsum = (float*)(smem + 131072 + 18432);   // [32] combined bias

    const int bid  = blockIdx.x;
    const int d    = bid >> 7;
    const int l    = (bid >> 6) & 1;
    const int s    = bid & 63;
    const int gid  = d * 2 + l;
    const int tid  = threadIdx.x;
    const int lane = tid & 63;
    const int kq   = tid >> 6;
    const int half = kq >> 2;
    const int kb   = kq & 3;
    const int lrow = lane & 15;
    const int quad = lane >> 4;

    const float* Wih = (d ? Wb_ih : Wf_ih) + (size_t)l * (2048 * 512);
    const float* Whh = (d ? Wb_hh : Wf_hh) + (size_t)l * (2048 * 512);

    if (tid < 32) {
        int g = tid >> 3, c = tid & 7;
        int grow = g * 512 + s * 8 + c;
        bsum[tid] = (d ? bb_ih : bf_ih)[l * 2048 + grow] + (d ? bb_hh : bf_hh)[l * 2048 + grow];
    }

    // zero pbuf once (steady-state: epilogue re-zeroes cells after reading)
    for (int i = tid; i < 4608; i += 512) pbuf[i] = 0.0f;

    // one-time weight fill: each wave writes exactly the fragments it will read.
    {
        const float* Wsrc = half ? Whh : Wih;
        bf16x8* w8 = (bf16x8*)wlds;
#pragma unroll
        for (int j = 0; j < 4; ++j)
#pragma unroll
            for (int nt = 0; nt < 2; ++nt) {
                int n    = nt * 16 + lrow;
                int grow = (n >> 3) * 512 + s * 8 + (n & 7);
                const float* src = Wsrc + (size_t)grow * 512 + (kb * 128 + j * 32 + quad * 8);
                bf16x8 vh, vl;
#pragma unroll
                for (int e = 0; e < 8; ++e) {
                    float v = src[e];
                    bf16_t hb = (bf16_t)v;
                    vh[e] = hb;
                    vl[e] = (bf16_t)(v - (float)hb);
                }
                int cidx = ((kq * 4 + j) * 2 + nt) * 2;
                w8[(size_t)cidx * 64 + lane]       = vh;
                w8[(size_t)(cidx + 1) * 64 + lane] = vl;
            }
    }
    __syncthreads();

    const bf16x8* wv8 = (const bf16x8*)wlds + (size_t)kq * 1024 + lane;
    const int aoff = lrow * 512 + kb * 128 + quad * 8;
    const bool xwave = (half == 0) && (l == 0);   // wave-uniform: reads x (cached)

    // persistent cell state: epilogue thread (tid<256) owns (b = tid>>3, c = tid&7)
    float creg = 0.0f;

#pragma unroll 1
    for (int t = 0; t < SS; ++t) {
        const int slot_c = t & 3, slot_p = (t + 3) & 3;

        // A fragments per j: hi-rows0-15 / hi-rows16-31 / lo-rows0-15 / lo-rows16-31
        u32x4 rA0[4], rA1[4], rB0[4], rB1[4];

        // ---- x prefetch (no flag dependency): in flight during the poll ----
        if (xwave) {
            int t_x = d ? (SS - 1 - t) : t;
            const bf16_t* ah = x_hi + (size_t)t_x * 16384 + aoff;
            const bf16_t* al = x_lo + (size_t)t_x * 16384 + aoff;
#pragma unroll
            for (int j = 0; j < 4; ++j) {
                rA0[j] = *(const u32x4*)(ah + j * 32);
                rA1[j] = *(const u32x4*)(ah + 8192 + j * 32);
                rB0[j] = *(const u32x4*)(al + j * 32);
                rB1[j] = *(const u32x4*)(al + 8192 + j * 32);
            }
        }

        // ---- wave 7 polls 64 flags lane-parallel (no vmem in flight here) ----
        if (tid >= 448) {
            const int ln = tid & 63;
            const int *fA, *fB; int tA, tB;
            if (l == 0) { fA = flg + gid * 64;       tA = t;
                          fB = flg + (gid + 1) * 64; tB = t - 3; }   // ring guard
            else        { fA = flg + (gid - 1) * 64; tA = t + 1;     // h0(t) ready
                          fB = flg + gid * 64;       tB = t; }
            for (;;) {
                int a = __hip_atomic_load(fA + ln, __ATOMIC_RELAXED, __HIP_MEMORY_SCOPE_AGENT);
                int b = __hip_atomic_load(fB + ln, __ATOMIC_RELAXED, __HIP_MEMORY_SCOPE_AGENT);
                if (__all((a >= tA) && (b >= tB))) break;
            }
        }
        __syncthreads();   // B1

        // ---- h-panel loads: agent-scope sc1 bypass, j-major, staged waits ----
        if (!xwave) {
            const bf16_t *pH, *pL;
            if (half == 0) {   // l==1 input half: layer-0 h at current slot
                pH = h_hi + (size_t)((d * 2) * 4 + slot_c) * 16384;
                pL = h_lo + (size_t)((d * 2) * 4 + slot_c) * 16384;
            } else {           // recurrent half: own gid h(t-1)
                pH = h_hi + (size_t)(gid * 4 + slot_p) * 16384;
                pL = h_lo + (size_t)(gid * 4 + slot_p) * 16384;
            }
            const bf16_t* ah  = pH + aoff;
            const bf16_t* ah2 = ah + 8192;
            const bf16_t* al  = pL + aoff;
            const bf16_t* al2 = al + 8192;
            // issue order = j-major; trailing vmcnt(8) makes j0/j1 data valid.
            asm volatile(
                "global_load_dwordx4 %0, %16, off sc1\n\t"
                "global_load_dwordx4 %4, %17, off sc1\n\t"
                "global_load_dwordx4 %8, %18, off sc1\n\t"
                "global_load_dwordx4 %12, %19, off sc1\n\t"
                "global_load_dwordx4 %1, %16, off offset:64 sc1\n\t"
                "global_load_dwordx4 %5, %17, off offset:64 sc1\n\t"
                "global_load_dwordx4 %9, %18, off offset:64 sc1\n\t"
                "global_load_dwordx4 %13, %19, off offset:64 sc1\n\t"
                "global_load_dwordx4 %2, %16, off offset:128 sc1\n\t"
                "global_load_dwordx4 %6, %17, off offset:128 sc1\n\t"
                "global_load_dwordx4 %10, %18, off offset:128 sc1\n\t"
                "global_load_dwordx4 %14, %19, off offset:128 sc1\n\t"
                "global_load_dwordx4 %3, %16, off offset:192 sc1\n\t"
                "global_load_dwordx4 %7, %17, off offset:192 sc1\n\t"
                "global_load_dwordx4 %11, %18, off offset:192 sc1\n\t"
                "global_load_dwordx4 %15, %19, off offset:192 sc1\n\t"
                "s_waitcnt vmcnt(8)"
                : "=&v"(rA0[0]), "=&v"(rA0[1]), "=&v"(rA0[2]), "=&v"(rA0[3]),
                  "=&v"(rA1[0]), "=&v"(rA1[1]), "=&v"(rA1[2]), "=&v"(rA1[3]),
                  "=&v"(rB0[0]), "=&v"(rB0[1]), "=&v"(rB0[2]), "=&v"(rB0[3]),
                  "=&v"(rB1[0]), "=&v"(rB1[1]), "=&v"(rB1[2]), "=&v"(rB1[3])
                : "v"(ah), "v"(ah2), "v"(al), "v"(al2)
                : "memory");
        }

        floatx4 acc00 = {0,0,0,0}, acc01 = {0,0,0,0}, acc10 = {0,0,0,0}, acc11 = {0,0,0,0};
#pragma unroll
        for (int j = 0; j < 4; ++j) {
            if (j == 2 && !xwave) {
                // j2/j3 fragments become valid; register ties prevent MFMA hoisting.
                asm volatile("s_waitcnt vmcnt(0)"
                             : "+v"(rA0[2]), "+v"(rA0[3]), "+v"(rA1[2]), "+v"(rA1[3]),
                               "+v"(rB0[2]), "+v"(rB0[3]), "+v"(rB1[2]), "+v"(rB1[3]));
            }
            bf16x8 b0h = wv8[j * 256];
            bf16x8 b0l = wv8[j * 256 + 64];
            bf16x8 b1h = wv8[j * 256 + 128];
            bf16x8 b1l = wv8[j * 256 + 192];
            bf16x8 ah0 = as_bf16x8(rA0[j]);
            bf16x8 ah1 = as_bf16x8(rA1[j]);
            bf16x8 al0 = as_bf16x8(rB0[j]);
            bf16x8 al1 = as_bf16x8(rB1[j]);
            acc00 = __builtin_amdgcn_mfma_f32_16x16x32_bf16(ah0, b0h, acc00, 0, 0, 0);
            acc00 = __builtin_amdgcn_mfma_f32_16x16x32_bf16(ah0, b0l, acc00, 0, 0, 0);
            acc00 = __builtin_amdgcn_mfma_f32_16x16x32_bf16(al0, b0h, acc00, 0, 0, 0);
            acc01 = __builtin_amdgcn_mfma_f32_16x16x32_bf16(ah0, b1h, acc01, 0, 0, 0);
            acc01 = __builtin_amdgcn_mfma_f32_16x16x32_bf16(ah0, b1l, acc01, 0, 0, 0);
            acc01 = __builtin_amdgcn_mfma_f32_16x16x32_bf16(al0, b1h, acc01, 0, 0, 0);
            acc10 = __builtin_amdgcn_mfma_f32_16x16x32_bf16(ah1, b0h, acc10, 0, 0, 0);
            acc10 = __builtin_amdgcn_mfma_f32_16x16x32_bf16(ah1, b0l, acc10, 0, 0, 0);
            acc10 = __builtin_amdgcn_mfma_f32_16x16x32_bf16(al1, b0h, acc10, 0, 0, 0);
            acc11 = __builtin_amdgcn_mfma_f32_16x16x32_bf16(ah1, b1h, acc11, 0, 0, 0);
            acc11 = __builtin_amdgcn_mfma_f32_16x16x32_bf16(ah1, b1l, acc11, 0, 0, 0);
            acc11 = __builtin_amdgcn_mfma_f32_16x16x32_bf16(al1, b1h, acc11, 0, 0, 0);
        }

        // ---- k-partial accumulate: ds_add_f32 from all 8 waves (2 adds/cell,
        //      commutative onto zeroed base -> deterministic) ----
        {
            float* pb = pbuf + kb * 1152;
#pragma unroll
            for (int rg = 0; rg < 4; ++rg) {
                atomicAdd(pb + (quad * 4 + rg) * 36 + lrow,           acc00[rg]);
                atomicAdd(pb + (quad * 4 + rg) * 36 + 16 + lrow,      acc01[rg]);
                atomicAdd(pb + (16 + quad * 4 + rg) * 36 + lrow,      acc10[rg]);
                atomicAdd(pb + (16 + quad * 4 + rg) * 36 + 16 + lrow, acc11[rg]);
            }
        }
        __syncthreads();   // B2

        // ---- epilogue: 256 threads, one (batch, col) each; c in register ----
        bf16_t hh_keep = (bf16_t)0.0f;
        if (tid < 256) {
            int b = tid >> 3, c = tid & 7;
            float gi = 0.f, gf = 0.f, gg = 0.f, go = 0.f;
#pragma unroll
            for (int kbb = 0; kbb < 4; ++kbb) {
                int base = kbb * 1152 + b * 36 + c;
                gi += pbuf[base];
                gf += pbuf[base + 8];
                gg += pbuf[base + 16];
                go += pbuf[base + 24];
                pbuf[base]      = 0.f;   // re-zero for next step's ds_adds
                pbuf[base + 8]  = 0.f;
                pbuf[base + 16] = 0.f;
                pbuf[base + 24] = 0.f;
            }
            gi += bsum[c]; gf += bsum[8 + c]; gg += bsum[16 + c]; go += bsum[24 + c];
            float cn = sigmoidf_(gf) * creg + sigmoidf_(gi) * tanhf(gg);
            float hn = sigmoidf_(go) * tanhf(cn);
            creg = cn;
            bf16_t hh = (bf16_t)hn;
            bf16_t hl = (bf16_t)(hn - (float)hh);
            hh_keep = hh;
            int col = s * 8 + c;
            size_t ho = (size_t)(gid * 4 + slot_c) * 16384 + (size_t)b * HH + col;
            // sc1 write-through to MALL so cross-XCD readers see it; drain before barrier.
            unsigned int vh = (unsigned int)__builtin_bit_cast(unsigned short, hh);
            unsigned int vl = (unsigned int)__builtin_bit_cast(unsigned short, hl);
            const bf16_t* ph = h_hi + ho;
            const bf16_t* pl = h_lo + ho;
            asm volatile(
                "global_store_short %0, %2, off sc1\n\t"
                "global_store_short %1, %3, off sc1\n\t"
                "s_waitcnt vmcnt(0)"
                :: "v"(ph), "v"(pl), "v"(vh), "v"(vl)
                : "memory");
        }

        // ---- arrive: barrier (producers drained) then plain flag store ----
        __syncthreads();   // B3
        if (tid == 0) {
            __hip_atomic_store(flg + gid * 64 + s, t + 1,
                               __ATOMIC_RELAXED, __HIP_MEMORY_SCOPE_AGENT);
        }
        // hout store after the flag: nothing waits on it (consumed by proj_gemm).
        if (l == 1 && tid < 256) {
            int b = tid >> 3, c = tid & 7;
            int col = s * 8 + c;
            int t_x = d ? (SS - 1 - t) : t;
            hout[((size_t)(d * SS + t_x) * BB + b) * HH + col] = hh_keep;
        }
    }
}

// ---------------- projection GEMM ----------------
__global__ __launch_bounds__(256)
void proj_gemm(const bf16_t* __restrict__ hA, const bf16_t* __restrict__ Wp,
               const float* __restrict__ b_fwd, const float* __restrict__ b_bwd,
               float* __restrict__ out)
{
    const int bid = blockIdx.x;
    const int nb  = (bid & 7) + ((bid >> 8) << 3);
    const int mb  = (bid >> 3) & 31;
    if (nb >= 63) return;
    const int d  = blockIdx.z;
    const int n0 = nb * 128;
    const int m0 = mb * 128;
    const bf16_t* A  = hA + (size_t)d * (SS * BB * HH);
    const bf16_t* Bw = Wp + (size_t)d * ((size_t)VPAD * HH);
    const float* bias = d ? b_bwd : b_fwd;
    float* O = out + (size_t)d * ((size_t)SS * BB * VV);

    __shared__ __align__(16) bf16_t lds_a[128 * 40];
    __shared__ __align__(16) bf16_t lds_b[128 * 40];

    const int tid  = threadIdx.x;
    const int lane = tid & 63;
    const int wv   = tid >> 6;
    const int wm   = wv >> 1, wn = wv & 1;
    const int lrow = lane & 15, quad = lane >> 4;

    floatx4 acc[4][4];
#pragma unroll
    for (int i = 0; i < 4; ++i)
#pragma unroll
        for (int j = 0; j < 4; ++j) acc[i][j] = (floatx4){0.f, 0.f, 0.f, 0.f};

    for (int k0 = 0; k0 < HH; k0 += 32) {
        __syncthreads();
#pragma unroll
        for (int q2 = 0; q2 < 2; ++q2) {
            int q = tid * 2 + q2;
            int row = q >> 2, cc = (q & 3) * 8;
            *(bf16x8*)(&lds_a[row * 40 + cc]) = *(const bf16x8*)(A  + (size_t)(m0 + row) * HH + k0 + cc);
            *(bf16x8*)(&lds_b[row * 40 + cc]) = *(const bf16x8*)(Bw + (size_t)(n0 + row) * HH + k0 + cc);
        }
        __syncthreads();
        bf16x8 af[4], bf4[4];
#pragma unroll
        for (int i = 0; i < 4; ++i) {
            af[i]  = *(const bf16x8*)(&lds_a[(wm * 64 + i * 16 + lrow) * 40 + quad * 8]);
            bf4[i] = *(const bf16x8*)(&lds_b[(wn * 64 + i * 16 + lrow) * 40 + quad * 8]);
        }
#pragma unroll
        for (int i = 0; i < 4; ++i)
#pragma unroll
            for (int j = 0; j < 4; ++j)
                acc[i][j] = __builtin_amdgcn_mfma_f32_16x16x32_bf16(af[i], bf4[j], acc[i][j], 0, 0, 0);
    }

#pragma unroll
    for (int j = 0; j < 4; ++j) {
        int n = n0 + wn * 64 + j * 16 + lrow;
        if (n < VV) {
            float bv = bias[n];
#pragma unroll
            for (int i = 0; i < 4; ++i) {
                int mbase = m0 + wm * 64 + i * 16 + quad * 4;
#pragma unroll
                for (int rg = 0; rg < 4; ++rg)
                    O[(size_t)(mbase + rg) * VV + n] = acc[i][j][rg] + bv;
            }
        }
    }
}

// ---------------- launch ----------------

extern "C" void kernel_launch(void* const* d_in, const int* in_sizes, int n_in,
                              void* d_out, int out_size, void* d_ws, size_t ws_size,
                              hipStream_t stream)
{
    const float* x     = (const float*)d_in[0];
    const float* Wf_ih = (const float*)d_in[1];
    const float* Wf_hh = (const float*)d_in[2];
    const float* bf_ih = (const float*)d_in[3];
    const float* bf_hh = (const float*)d_in[4];
    const float* Wb_ih = (const float*)d_in[5];
    const float* Wb_hh = (const float*)d_in[6];
    const float* bb_ih = (const float*)d_in[7];
    const float* bb_hh = (const float*)d_in[8];
    const float* W_fwd = (const float*)d_in[9];
    const float* b_fwd = (const float*)d_in[10];
    const float* W_bwd = (const float*)d_in[11];
    const float* b_bwd = (const float*)d_in[12];
    float* out = (float*)d_out;
    (void)in_sizes; (void)n_in; (void)out_size; (void)ws_size;

    char* ws = (char*)d_ws;
    int*    flg  = (int*)   (ws + WS_FLG);
    bf16_t* h_hi = (bf16_t*)(ws + WS_HHI);
    bf16_t* h_lo = (bf16_t*)(ws + WS_HLO);
    bf16_t* x_hi = (bf16_t*)(ws + WS_XHI);
    bf16_t* x_lo = (bf16_t*)(ws + WS_XLO);
    bf16_t* hout = (bf16_t*)(ws + WS_HOUT);
    bf16_t* Wp   = (bf16_t*)(ws + WS_WP);

    (void)hipFuncSetAttribute(reinterpret_cast<const void*>(lstm_persist),
                              hipFuncAttributeMaxDynamicSharedMemorySize, SMEM_BYTES);

    hipMemsetAsync(ws, 0, MEMSET_BYTES, stream);

    prep_x <<<dim3(8192),  256, 0, stream>>>(x, x_hi, x_lo);
    prep_wp<<<dim3(32256), 256, 0, stream>>>(W_fwd, W_bwd, Wp);

    lstm_persist<<<dim3(256), dim3(512), SMEM_BYTES, stream>>>(
        Wf_ih, Wf_hh, Wb_ih, Wb_hh, bf_ih, bf_hh, bb_ih, bb_hh,
        x_hi, x_lo, h_hi, h_lo, hout, flg);

    proj_gemm<<<dim3(2048, 1, 2), 256, 0, stream>>>(hout, Wp, b_fwd, b_bwd, out);
}

// Round 4
// 1501.185 us; speedup vs baseline: 1.6706x; 1.6706x over previous
//
#include <hip/hip_runtime.h>

#define SS 128
#define BB 32
#define HH 512
#define VV 8000
#define VPAD 8064

typedef __bf16 bf16_t;
typedef __bf16 bf16x8 __attribute__((ext_vector_type(8)));
typedef float  floatx4 __attribute__((ext_vector_type(4)));
typedef unsigned int u32x4 __attribute__((ext_vector_type(4)));

__device__ __forceinline__ float sigmoidf_(float x) { return 1.0f / (1.0f + expf(-x)); }
__device__ __forceinline__ bf16x8 as_bf16x8(u32x4 v) { return __builtin_bit_cast(bf16x8, v); }

// ---------------- workspace layout (bytes) ----------------
#define WS_FLG   0                       // flags[4][64] int = 1024 B (per-WG "steps done")
#define WS_HHI   1024                    // h ring hi [2d][2l][4 slot][32][512] bf16 = 524288
#define WS_HLO   (WS_HHI + 524288)       // h ring lo = 524288
#define WS_XHI   (WS_HLO + 524288)       // x hi [128][32][512] bf16 = 4194304
#define WS_XLO   (WS_XHI + 4194304)      // x lo = 4194304
#define WS_HOUT  (WS_XLO + 4194304)      // top-layer h [2][128][32][512] bf16 = 8388608
#define WS_WP    (WS_HOUT + 8388608)     // proj weights [2][8064][512] bf16 = 16515072
#define MEMSET_BYTES WS_XHI              // zero flags + h ring

// LDS: weights 131072 + pbuf 4*32*36*4 = 18432 + bsum 128 -> 149632 (< 160 KiB)
#define SMEM_BYTES 149632

// ---------------- prep kernels ----------------

__global__ __launch_bounds__(256)
void prep_x(const float* __restrict__ x, bf16_t* __restrict__ xh, bf16_t* __restrict__ xl) {
    int i = blockIdx.x * 256 + threadIdx.x;   // 128*32*512 = 2097152 exact
    float v = x[i];
    bf16_t h = (bf16_t)v;
    xh[i] = h;
    xl[i] = (bf16_t)(v - (float)h);
}

__global__ __launch_bounds__(256)
void prep_wp(const float* __restrict__ Wf, const float* __restrict__ Wb, bf16_t* __restrict__ Wp) {
    int i = blockIdx.x * 256 + threadIdx.x;   // 2*8064*512 = 8257536 exact
    int k   = i & 511;
    int rd  = i >> 9;
    int row = rd % 8064;
    int d   = rd / 8064;
    const float* W = d ? Wb : Wf;
    Wp[i] = (row < VV) ? (bf16_t)W[(size_t)row * 512 + k] : (bf16_t)0.0f;
}

// ---------------- persistent LSTM ----------------
// 256 WGs x 512 thr, 1 WG/CU. WG = (d, l, s): 8 h-cols x 4 gates of one (dir,layer).
// Weights (split hi/lo) in LDS, pre-swizzled MFMA fragment order.
// Wave kq (0..7): half = kq>>2 (0: input A, 1: recurrent A), kb = kq&3 (128-k block).
//
// Sync design (R3, resubmitted R4 — R3 bench was an infra failure, no counters):
//  - PER-WAVE dependency polls, NO load-side barrier: each wave polls exactly the
//    64 flags it needs (lane-parallel, s_sleep(2) backoff — R2 proved unthrottled
//    spinning collapses the MALL flag lines), then immediately issues its loads.
//      l=0 waves 0-3 (x):        no poll
//      waves 4-7 (own h(t-1)):   flg[gid]   >= t
//      l=1 waves 0-3 (h0(t)):    flg[gid-1] >= t+1
//    Ring guard (l=0 only) moved to the epilogue, before the h-store.
//    Deadlock-freedom: flag_l0(t+1) <- flag_l1(t-3) <- flag_l0(t-3) <- ... strictly
//    decreasing thresholds, base case t<4 unguarded; d-chains disjoint; acyclic.
//  - Two-phase pbuf (write then add, NO ds atomics — R2's atomicAdd doubled LDS
//    bank conflicts). 3 barriers/step.
//  - sc1 h stores (write-through to MALL) / sc1 h loads, staged vmcnt. No fences.

__global__ __launch_bounds__(512, 2)
void lstm_persist(const float* __restrict__ Wf_ih, const float* __restrict__ Wf_hh,
                  const float* __restrict__ Wb_ih, const float* __restrict__ Wb_hh,
                  const float* __restrict__ bf_ih, const float* __restrict__ bf_hh,
                  const float* __restrict__ bb_ih, const float* __restrict__ bb_hh,
                  const bf16_t* __restrict__ x_hi, const bf16_t* __restrict__ x_lo,
                  bf16_t* __restrict__ h_hi, bf16_t* __restrict__ h_lo,
                  bf16_t* __restrict__ hout, int* __restrict__ flg)
{
    extern __shared__ char smem[];
    bf16_t* wlds = (bf16_t*)smem;                     // 128 KB weight fragments
    float*  pbuf = (float*)(smem + 131072);           // [4 kb][32 row][36] k-partials
    float*  bsum = (float*)(smem + 131072 + 18432);   // [32] combined bias

    const int bid  = blockIdx.x;
    const int d    = bid >> 7;
    const int l    = (bid >> 6) & 1;
    const int s    = bid & 63;
    const int gid  = d * 2 + l;
    const int tid  = threadIdx.x;
    const int lane = tid & 63;
    const int kq   = tid >> 6;
    const int half = kq >> 2;
    const int kb   = kq & 3;
    const int lrow = lane & 15;
    const int quad = lane >> 4;

    const float* Wih = (d ? Wb_ih : Wf_ih) + (size_t)l * (2048 * 512);
    const float* Whh = (d ? Wb_hh : Wf_hh) + (size_t)l * (2048 * 512);

    if (tid < 32) {
        int g = tid >> 3, c = tid & 7;
        int grow = g * 512 + s * 8 + c;
        bsum[tid] = (d ? bb_ih : bf_ih)[l * 2048 + grow] + (d ? bb_hh : bf_hh)[l * 2048 + grow];
    }

    // one-time weight fill: each wave writes exactly the fragments it will read.
    {
        const float* Wsrc = half ? Whh : Wih;
        bf16x8* w8 = (bf16x8*)wlds;
#pragma unroll
        for (int j = 0; j < 4; ++j)
#pragma unroll
            for (int nt = 0; nt < 2; ++nt) {
                int n    = nt * 16 + lrow;
                int grow = (n >> 3) * 512 + s * 8 + (n & 7);
                const float* src = Wsrc + (size_t)grow * 512 + (kb * 128 + j * 32 + quad * 8);
                bf16x8 vh, vl;
#pragma unroll
                for (int e = 0; e < 8; ++e) {
                    float v = src[e];
                    bf16_t hb = (bf16_t)v;
                    vh[e] = hb;
                    vl[e] = (bf16_t)(v - (float)hb);
                }
                int cidx = ((kq * 4 + j) * 2 + nt) * 2;
                w8[(size_t)cidx * 64 + lane]       = vh;
                w8[(size_t)(cidx + 1) * 64 + lane] = vl;
            }
    }
    __syncthreads();

    const bf16x8* wv8 = (const bf16x8*)wlds + (size_t)kq * 1024 + lane;
    const int aoff = lrow * 512 + kb * 128 + quad * 8;
    const bool xwave = (half == 0) && (l == 0);   // wave-uniform: reads x (cached)

    // per-wave flag pointer + threshold offset (wave-uniform)
    const int* wflag = nullptr;   // 64 flags this wave polls
    int  woff = 0;                // threshold = t + woff
    if (half == 1)      { wflag = flg + gid * 64;       woff = 0; }
    else if (l == 1)    { wflag = flg + (gid - 1) * 64; woff = 1; }

    // persistent cell state: epilogue thread (tid<256) owns (b = tid>>3, c = tid&7)
    float creg = 0.0f;

#pragma unroll 1
    for (int t = 0; t < SS; ++t) {
        const int slot_c = t & 3, slot_p = (t + 3) & 3;

        // A fragments per j: hi-rows0-15 / hi-rows16-31 / lo-rows0-15 / lo-rows16-31
        u32x4 rA0[4], rA1[4], rB0[4], rB1[4];

        // ---- per-wave dependency poll (lane-parallel over 64 flags) ----
        if (wflag) {
            const int thr = t + woff;
            for (;;) {
                int v = __hip_atomic_load(wflag + lane, __ATOMIC_RELAXED, __HIP_MEMORY_SCOPE_AGENT);
                if (__all(v >= thr)) break;
                __builtin_amdgcn_s_sleep(2);
            }
        }

        // ---- A loads, issued as soon as THIS wave's dependency cleared ----
        if (xwave) {
            int t_x = d ? (SS - 1 - t) : t;
            const bf16_t* ah = x_hi + (size_t)t_x * 16384 + aoff;
            const bf16_t* al = x_lo + (size_t)t_x * 16384 + aoff;
#pragma unroll
            for (int j = 0; j < 4; ++j) {
                rA0[j] = *(const u32x4*)(ah + j * 32);
                rA1[j] = *(const u32x4*)(ah + 8192 + j * 32);
                rB0[j] = *(const u32x4*)(al + j * 32);
                rB1[j] = *(const u32x4*)(al + 8192 + j * 32);
            }
        } else {
            const bf16_t *pH, *pL;
            if (half == 0) {   // l==1 input half: layer-0 h at current slot
                pH = h_hi + (size_t)((d * 2) * 4 + slot_c) * 16384;
                pL = h_lo + (size_t)((d * 2) * 4 + slot_c) * 16384;
            } else {           // recurrent half: own gid h(t-1)
                pH = h_hi + (size_t)(gid * 4 + slot_p) * 16384;
                pL = h_lo + (size_t)(gid * 4 + slot_p) * 16384;
            }
            const bf16_t* ah  = pH + aoff;
            const bf16_t* ah2 = ah + 8192;
            const bf16_t* al  = pL + aoff;
            const bf16_t* al2 = al + 8192;
            // issue order = j-major; trailing vmcnt(8) makes j0/j1 data valid.
            asm volatile(
                "global_load_dwordx4 %0, %16, off sc1\n\t"
                "global_load_dwordx4 %4, %17, off sc1\n\t"
                "global_load_dwordx4 %8, %18, off sc1\n\t"
                "global_load_dwordx4 %12, %19, off sc1\n\t"
                "global_load_dwordx4 %1, %16, off offset:64 sc1\n\t"
                "global_load_dwordx4 %5, %17, off offset:64 sc1\n\t"
                "global_load_dwordx4 %9, %18, off offset:64 sc1\n\t"
                "global_load_dwordx4 %13, %19, off offset:64 sc1\n\t"
                "global_load_dwordx4 %2, %16, off offset:128 sc1\n\t"
                "global_load_dwordx4 %6, %17, off offset:128 sc1\n\t"
                "global_load_dwordx4 %10, %18, off offset:128 sc1\n\t"
                "global_load_dwordx4 %14, %19, off offset:128 sc1\n\t"
                "global_load_dwordx4 %3, %16, off offset:192 sc1\n\t"
                "global_load_dwordx4 %7, %17, off offset:192 sc1\n\t"
                "global_load_dwordx4 %11, %19, off offset:192 sc1\n\t"
                "global_load_dwordx4 %15, %19, off offset:192 sc1\n\t"
                "s_waitcnt vmcnt(8)"
                : "=&v"(rA0[0]), "=&v"(rA0[1]), "=&v"(rA0[2]), "=&v"(rA0[3]),
                  "=&v"(rA1[0]), "=&v"(rA1[1]), "=&v"(rA1[2]), "=&v"(rA1[3]),
                  "=&v"(rB0[0]), "=&v"(rB0[1]), "=&v"(rB0[2]), "=&v"(rB0[3]),
                  "=&v"(rB1[0]), "=&v"(rB1[1]), "=&v"(rB1[2]), "=&v"(rB1[3])
                : "v"(ah), "v"(ah2), "v"(al), "v"(al2)
                : "memory");
        }

        floatx4 acc00 = {0,0,0,0}, acc01 = {0,0,0,0}, acc10 = {0,0,0,0}, acc11 = {0,0,0,0};
#pragma unroll
        for (int j = 0; j < 4; ++j) {
            if (j == 2 && !xwave) {
                // j2/j3 fragments become valid; register ties prevent MFMA hoisting.
                asm volatile("s_waitcnt vmcnt(0)"
                             : "+v"(rA0[2]), "+v"(rA0[3]), "+v"(rA1[2]), "+v"(rA1[3]),
                               "+v"(rB0[2]), "+v"(rB0[3]), "+v"(rB1[2]), "+v"(rB1[3]));
            }
            bf16x8 b0h = wv8[j * 256];
            bf16x8 b0l = wv8[j * 256 + 64];
            bf16x8 b1h = wv8[j * 256 + 128];
            bf16x8 b1l = wv8[j * 256 + 192];
            bf16x8 ah0 = as_bf16x8(rA0[j]);
            bf16x8 ah1 = as_bf16x8(rA1[j]);
            bf16x8 al0 = as_bf16x8(rB0[j]);
            bf16x8 al1 = as_bf16x8(rB1[j]);
            acc00 = __builtin_amdgcn_mfma_f32_16x16x32_bf16(ah0, b0h, acc00, 0, 0, 0);
            acc00 = __builtin_amdgcn_mfma_f32_16x16x32_bf16(ah0, b0l, acc00, 0, 0, 0);
            acc00 = __builtin_amdgcn_mfma_f32_16x16x32_bf16(al0, b0h, acc00, 0, 0, 0);
            acc01 = __builtin_amdgcn_mfma_f32_16x16x32_bf16(ah0, b1h, acc01, 0, 0, 0);
            acc01 = __builtin_amdgcn_mfma_f32_16x16x32_bf16(ah0, b1l, acc01, 0, 0, 0);
            acc01 = __builtin_amdgcn_mfma_f32_16x16x32_bf16(al0, b1h, acc01, 0, 0, 0);
            acc10 = __builtin_amdgcn_mfma_f32_16x16x32_bf16(ah1, b0h, acc10, 0, 0, 0);
            acc10 = __builtin_amdgcn_mfma_f32_16x16x32_bf16(ah1, b0l, acc10, 0, 0, 0);
            acc10 = __builtin_amdgcn_mfma_f32_16x16x32_bf16(al1, b0h, acc10, 0, 0, 0);
            acc11 = __builtin_amdgcn_mfma_f32_16x16x32_bf16(ah1, b1h, acc11, 0, 0, 0);
            acc11 = __builtin_amdgcn_mfma_f32_16x16x32_bf16(ah1, b1l, acc11, 0, 0, 0);
            acc11 = __builtin_amdgcn_mfma_f32_16x16x32_bf16(al1, b1h, acc11, 0, 0, 0);
        }

        // ---- k-partial reduce, two-phase (no LDS atomics) ----
        if (half == 0) {
#pragma unroll
            for (int rg = 0; rg < 4; ++rg) {
                pbuf[kb * 1152 + (quad * 4 + rg) * 36 + lrow]           = acc00[rg];
                pbuf[kb * 1152 + (quad * 4 + rg) * 36 + 16 + lrow]      = acc01[rg];
                pbuf[kb * 1152 + (16 + quad * 4 + rg) * 36 + lrow]      = acc10[rg];
                pbuf[kb * 1152 + (16 + quad * 4 + rg) * 36 + 16 + lrow] = acc11[rg];
            }
        }
        __syncthreads();   // B_a: write -> add
        if (half == 1) {
#pragma unroll
            for (int rg = 0; rg < 4; ++rg) {
                pbuf[kb * 1152 + (quad * 4 + rg) * 36 + lrow]           += acc00[rg];
                pbuf[kb * 1152 + (quad * 4 + rg) * 36 + 16 + lrow]      += acc01[rg];
                pbuf[kb * 1152 + (16 + quad * 4 + rg) * 36 + lrow]      += acc10[rg];
                pbuf[kb * 1152 + (16 + quad * 4 + rg) * 36 + 16 + lrow] += acc11[rg];
            }
        }
        __syncthreads();   // B_b: add -> epilogue read

        // ---- epilogue: 256 threads, one (batch, col) each; c in register ----
        bf16_t hh_keep = (bf16_t)0.0f;
        if (tid < 256) {
            // ring guard (l=0 only): h(t) store overwrites h(t-4); l+1 must have
            // finished step t-4 (loaded it). Poll before storing, not before MFMA.
            if (l == 0 && t >= 4) {
                const int* gf = flg + (gid + 1) * 64;
                const int thr = t - 3;
                for (;;) {
                    int v = __hip_atomic_load(gf + lane, __ATOMIC_RELAXED, __HIP_MEMORY_SCOPE_AGENT);
                    if (__all(v >= thr)) break;
                    __builtin_amdgcn_s_sleep(2);
                }
            }
            int b = tid >> 3, c = tid & 7;
            float gi = 0.f, gf_ = 0.f, gg = 0.f, go = 0.f;
#pragma unroll
            for (int kbb = 0; kbb < 4; ++kbb) {
                int base = kbb * 1152 + b * 36 + c;
                gi  += pbuf[base];
                gf_ += pbuf[base + 8];
                gg  += pbuf[base + 16];
                go  += pbuf[base + 24];
            }
            gi += bsum[c]; gf_ += bsum[8 + c]; gg += bsum[16 + c]; go += bsum[24 + c];
            float cn = sigmoidf_(gf_) * creg + sigmoidf_(gi) * tanhf(gg);
            float hn = sigmoidf_(go) * tanhf(cn);
            creg = cn;
            bf16_t hh = (bf16_t)hn;
            bf16_t hl = (bf16_t)(hn - (float)hh);
            hh_keep = hh;
            int col = s * 8 + c;
            size_t ho = (size_t)(gid * 4 + slot_c) * 16384 + (size_t)b * HH + col;
            // sc1 write-through to MALL so cross-XCD readers see it; drain before barrier.
            unsigned int vh = (unsigned int)__builtin_bit_cast(unsigned short, hh);
            unsigned int vl = (unsigned int)__builtin_bit_cast(unsigned short, hl);
            const bf16_t* ph = h_hi + ho;
            const bf16_t* pl = h_lo + ho;
            asm volatile(
                "global_store_short %0, %2, off sc1\n\t"
                "global_store_short %1, %3, off sc1\n\t"
                "s_waitcnt vmcnt(0)"
                :: "v"(ph), "v"(pl), "v"(vh), "v"(vl)
                : "memory");
        }

        // ---- arrive: barrier (producers drained) then plain flag store ----
        __syncthreads();   // B_c: epilogue read done + h stores drained
        if (tid == 0) {
            __hip_atomic_store(flg + gid * 64 + s, t + 1,
                               __ATOMIC_RELAXED, __HIP_MEMORY_SCOPE_AGENT);
        }
        // hout store after the flag: nothing waits on it (consumed by proj_gemm).
        if (l == 1 && tid < 256) {
            int b = tid >> 3, c = tid & 7;
            int col = s * 8 + c;
            int t_x = d ? (SS - 1 - t) : t;
            hout[((size_t)(d * SS + t_x) * BB + b) * HH + col] = hh_keep;
        }
    }
}

// ---------------- projection GEMM ----------------
__global__ __launch_bounds__(256)
void proj_gemm(const bf16_t* __restrict__ hA, const bf16_t* __restrict__ Wp,
               const float* __restrict__ b_fwd, const float* __restrict__ b_bwd,
               float* __restrict__ out)
{
    const int bid = blockIdx.x;
    const int nb  = (bid & 7) + ((bid >> 8) << 3);
    const int mb  = (bid >> 3) & 31;
    if (nb >= 63) return;
    const int d  = blockIdx.z;
    const int n0 = nb * 128;
    const int m0 = mb * 128;
    const bf16_t* A  = hA + (size_t)d * (SS * BB * HH);
    const bf16_t* Bw = Wp + (size_t)d * ((size_t)VPAD * HH);
    const float* bias = d ? b_bwd : b_fwd;
    float* O = out + (size_t)d * ((size_t)SS * BB * VV);

    __shared__ __align__(16) bf16_t lds_a[128 * 40];
    __shared__ __align__(16) bf16_t lds_b[128 * 40];

    const int tid  = threadIdx.x;
    const int lane = tid & 63;
    const int wv   = tid >> 6;
    const int wm   = wv >> 1, wn = wv & 1;
    const int lrow = lane & 15, quad = lane >> 4;

    floatx4 acc[4][4];
#pragma unroll
    for (int i = 0; i < 4; ++i)
#pragma unroll
        for (int j = 0; j < 4; ++j) acc[i][j] = (floatx4){0.f, 0.f, 0.f, 0.f};

    for (int k0 = 0; k0 < HH; k0 += 32) {
        __syncthreads();
#pragma unroll
        for (int q2 = 0; q2 < 2; ++q2) {
            int q = tid * 2 + q2;
            int row = q >> 2, cc = (q & 3) * 8;
            *(bf16x8*)(&lds_a[row * 40 + cc]) = *(const bf16x8*)(A  + (size_t)(m0 + row) * HH + k0 + cc);
            *(bf16x8*)(&lds_b[row * 40 + cc]) = *(const bf16x8*)(Bw + (size_t)(n0 + row) * HH + k0 + cc);
        }
        __syncthreads();
        bf16x8 af[4], bf4[4];
#pragma unroll
        for (int i = 0; i < 4; ++i) {
            af[i]  = *(const bf16x8*)(&lds_a[(wm * 64 + i * 16 + lrow) * 40 + quad * 8]);
            bf4[i] = *(const bf16x8*)(&lds_b[(wn * 64 + i * 16 + lrow) * 40 + quad * 8]);
        }
#pragma unroll
        for (int i = 0; i < 4; ++i)
#pragma unroll
            for (int j = 0; j < 4; ++j)
                acc[i][j] = __builtin_amdgcn_mfma_f32_16x16x32_bf16(af[i], bf4[j], acc[i][j], 0, 0, 0);
    }

#pragma unroll
    for (int j = 0; j < 4; ++j) {
        int n = n0 + wn * 64 + j * 16 + lrow;
        if (n < VV) {
            float bv = bias[n];
#pragma unroll
            for (int i = 0; i < 4; ++i) {
                int mbase = m0 + wm * 64 + i * 16 + quad * 4;
#pragma unroll
                for (int rg = 0; rg < 4; ++rg)
                    O[(size_t)(mbase + rg) * VV + n] = acc[i][j][rg] + bv;
            }
        }
    }
}

// ---------------- launch ----------------

extern "C" void kernel_launch(void* const* d_in, const int* in_sizes, int n_in,
                              void* d_out, int out_size, void* d_ws, size_t ws_size,
                              hipStream_t stream)
{
    const float* x     = (const float*)d_in[0];
    const float* Wf_ih = (const float*)d_in[1];
    const float* Wf_hh = (const float*)d_in[2];
    const float* bf_ih = (const float*)d_in[3];
    const float* bf_hh = (const float*)d_in[4];
    const float* Wb_ih = (const float*)d_in[5];
    const float* Wb_hh = (const float*)d_in[6];
    const float* bb_ih = (const float*)d_in[7];
    const float* bb_hh = (const float*)d_in[8];
    const float* W_fwd = (const float*)d_in[9];
    const float* b_fwd = (const float*)d_in[10];
    const float* W_bwd = (const float*)d_in[11];
    const float* b_bwd = (const float*)d_in[12];
    float* out = (float*)d_out;
    (void)in_sizes; (void)n_in; (void)out_size; (void)ws_size;

    char* ws = (char*)d_ws;
    int*    flg  = (int*)   (ws + WS_FLG);
    bf16_t* h_hi = (bf16_t*)(ws + WS_HHI);
    bf16_t* h_lo = (bf16_t*)(ws + WS_HLO);
    bf16_t* x_hi = (bf16_t*)(ws + WS_XHI);
    bf16_t* x_lo = (bf16_t*)(ws + WS_XLO);
    bf16_t* hout = (bf16_t*)(ws + WS_HOUT);
    bf16_t* Wp   = (bf16_t*)(ws + WS_WP);

    (void)hipFuncSetAttribute(reinterpret_cast<const void*>(lstm_persist),
                              hipFuncAttributeMaxDynamicSharedMemorySize, SMEM_BYTES);

    hipMemsetAsync(ws, 0, MEMSET_BYTES, stream);

    prep_x <<<dim3(8192),  256, 0, stream>>>(x, x_hi, x_lo);
    prep_wp<<<dim3(32256), 256, 0, stream>>>(W_fwd, W_bwd, Wp);

    lstm_persist<<<dim3(256), dim3(512), SMEM_BYTES, stream>>>(
        Wf_ih, Wf_hh, Wb_ih, Wb_hh, bf_ih, bf_hh, bb_ih, bb_hh,
        x_hi, x_lo, h_hi, h_lo, hout, flg);

    proj_gemm<<<dim3(2048, 1, 2), 256, 0, stream>>>(hout, Wp, b_fwd, b_bwd, out);
}